// Round 6
// baseline (510.281 us; speedup 1.0000x reference)
//
#include <hip/hip_runtime.h>
#include <stdint.h>

typedef unsigned short u16t;
typedef __attribute__((ext_vector_type(8))) short frag8;   // 8 x bf16 (4 VGPRs)
typedef __attribute__((ext_vector_type(4))) float facc4;   // MFMA accumulator

#define S_LEN 2048
#define E_DIM 2048

__device__ __forceinline__ u16t f2bf(float f) {
    union { float f; uint32_t u; } c; c.f = f;
    return (u16t)((c.u + 0x7fffu + ((c.u >> 16) & 1u)) >> 16);  // RNE
}

// ---------------- fp32 -> bf16 conversion (vectorized) ----------------
__global__ __launch_bounds__(256) void cvt_kernel(const float* __restrict__ src,
                                                  u16t* __restrict__ dst, int n4) {
    int i = blockIdx.x * 256 + threadIdx.x;
    if (i >= n4) return;
    float4 v = ((const float4*)src)[i];
    ushort4 o;
    o.x = f2bf(v.x); o.y = f2bf(v.y); o.z = f2bf(v.z); o.w = f2bf(v.w);
    ((ushort4*)dst)[i] = o;
}

// ---------------- async global->LDS, 16B per lane ----------------
__device__ __forceinline__ void gldl16(const u16t* g, u16t* l) {
    __builtin_amdgcn_global_load_lds(
        (__attribute__((address_space(1))) void*)(g),
        (__attribute__((address_space(3))) void*)(l), 16, 0, 0);
}

// =====================================================================
// 256x256 GEMM core (R1 variant -- measured best of 4 schedule variants:
// 233-235 us vs 240-246 for template-lockstep / read-ahead / asm-reads).
// 8 waves (2M x 4N), per-wave C = 128x64 -> acc[8][4]. K-tile BK=64 as 2
// ksub halves; 4 phases per K-tile, vmcnt(6) at 2 of them; compiler
// handles fine-grain lgkmcnt. XOR-swizzle (T2) via pre-swizzled global
// source + swizzled ds_read (bank conflicts measured 0).
// =====================================================================
__device__ __forceinline__ void gemm256(const u16t* __restrict__ A,
                                        const u16t* __restrict__ B,
                                        int bm0, int bn0,
                                        u16t* lds, facc4 acc[8][4]) {
    const int t     = threadIdx.x;
    const int lane  = t & 63;
    const int wid   = t >> 6;
    const int m16   = lane & 15;
    const int quad  = lane >> 4;
    const int wid_m = wid >> 2;     // 0..1
    const int wid_n = wid & 3;      // 0..3

#pragma unroll
    for (int i = 0; i < 8; ++i)
#pragma unroll
        for (int j = 0; j < 4; ++j) acc[i][j] = facc4{0.f, 0.f, 0.f, 0.f};

    // ---- frag read offsets (u16 units), swizzled ----
    const int colA = (((wid_m << 2) + quad) ^ (m16 & 7)) << 3;
    const int colB = ((((wid_n >> 1) << 2) + quad) ^ (m16 & 7)) << 3;
    const int roA  = m16 * 64 + colA;                        // + i*1024
    const int roB  = ((wid_n & 1) * 64 + m16) * 64 + colB;   // + j*1024

    // ---- staging lane geometry (inverse swizzle on global source) ----
    const int cp    = (lane & 7) ^ (lane >> 3);
    const int rgrp  = cp >> 2;
    const int qq    = cp & 3;
    const int line0 = wid * 8 + (lane >> 3);
    const u16t* pA[2]; const u16t* pB[2]; int dOf[2];
#pragma unroll
    for (int ld = 0; ld < 2; ++ld) {
        const int grow = rgrp * 128 + ld * 64 + line0;   // row within 256-tile
        pA[ld] = A + (size_t)(bm0 + grow) * E_DIM + qq * 8;
        pB[ld] = B + (size_t)(bn0 + grow) * E_DIM + qq * 8;
        dOf[ld] = (ld * 512 + wid * 64) * 8;             // lane-linear dest
    }

    // ---- prologue: stage tile 0 into dbuf 0 (order: A0 B0 A1 B1) ----
#pragma unroll
    for (int ld = 0; ld < 2; ++ld) gldl16(pA[ld],      lds +         dOf[ld]);
#pragma unroll
    for (int ld = 0; ld < 2; ++ld) gldl16(pB[ld],      lds + 16384 + dOf[ld]);
#pragma unroll
    for (int ld = 0; ld < 2; ++ld) gldl16(pA[ld] + 32, lds + 8192  + dOf[ld]);
#pragma unroll
    for (int ld = 0; ld < 2; ++ld) gldl16(pB[ld] + 32, lds + 24576 + dOf[ld]);

#define MFMA16(IB)                                                            \
    __builtin_amdgcn_s_setprio(1);                                            \
    _Pragma("unroll")                                                         \
    for (int i = 0; i < 4; ++i)                                               \
        _Pragma("unroll")                                                     \
        for (int j = 0; j < 4; ++j)                                           \
            acc[i + IB][j] = __builtin_amdgcn_mfma_f32_16x16x32_bf16(         \
                av[i], bv[j], acc[i + IB][j], 0, 0, 0);                       \
    __builtin_amdgcn_s_setprio(0);

#pragma unroll 2
    for (int t0 = 0; t0 < 32; ++t0) {
        const u16t* Lc = lds + (t0 & 1) * 32768;          // compute buffer
        u16t* Ln       = lds + ((t0 & 1) ^ 1) * 32768;    // stage buffer
        const int kn   = (t0 < 31) ? (t0 + 1) * 64 : 0;   // wrap on last tile
        frag8 av[4], bv[4];

        // ===== phase 1: ksub0, i = 0..3 =====
        gldl16(pA[0] + kn, Ln + dOf[0]);
        gldl16(pA[1] + kn, Ln + dOf[1]);
        asm volatile("s_waitcnt vmcnt(6)" ::: "memory");
        __builtin_amdgcn_s_barrier();
#pragma unroll
        for (int j = 0; j < 4; ++j) bv[j] = *(const frag8*)(Lc + 16384 + roB + j * 1024);
#pragma unroll
        for (int i = 0; i < 4; ++i) av[i] = *(const frag8*)(Lc + roA + i * 1024);
        MFMA16(0)

        // ===== phase 2: ksub0, i = 4..7 =====
        gldl16(pB[0] + kn, Ln + 16384 + dOf[0]);
        gldl16(pB[1] + kn, Ln + 16384 + dOf[1]);
#pragma unroll
        for (int i = 0; i < 4; ++i) av[i] = *(const frag8*)(Lc + roA + (i + 4) * 1024);
        MFMA16(4)

        // ===== phase 3: ksub1, i = 0..3 =====
        gldl16(pA[0] + kn + 32, Ln + 8192 + dOf[0]);
        gldl16(pA[1] + kn + 32, Ln + 8192 + dOf[1]);
        asm volatile("s_waitcnt vmcnt(6)" ::: "memory");
        __builtin_amdgcn_s_barrier();
#pragma unroll
        for (int j = 0; j < 4; ++j) bv[j] = *(const frag8*)(Lc + 24576 + roB + j * 1024);
#pragma unroll
        for (int i = 0; i < 4; ++i) av[i] = *(const frag8*)(Lc + 8192 + roA + i * 1024);
        MFMA16(0)

        // ===== phase 4: ksub1, i = 4..7 =====
        gldl16(pB[0] + kn + 32, Ln + 24576 + dOf[0]);
        gldl16(pB[1] + kn + 32, Ln + 24576 + dOf[1]);
#pragma unroll
        for (int i = 0; i < 4; ++i) av[i] = *(const frag8*)(Lc + 8192 + roA + (i + 4) * 1024);
        MFMA16(4)
    }
#undef MFMA16

    // drain the tail prefetch before epilogue / endpgm
    asm volatile("s_waitcnt vmcnt(0)" ::: "memory");
}

// bijective XCD-aware tile swizzle: 256 wgs per plane, 256 % 8 == 0.
__device__ __forceinline__ void tile_swz(int& bm0, int& bn0) {
    const int orig = blockIdx.y * 8 + blockIdx.x;
    const int swz  = (orig & 7) * 32 + (orig >> 3);
    bm0 = (swz >> 3) * 256;
    bn0 = (swz & 7) * 256;
}

// ---------------- QKV projection plane (+bias, +RoPE for q,k) ----------------
// Split into one launch per plane (q,k,v) so per-kernel rocprof rows for
// attn_kernel / out_gemm surface in the top-5 (diagnostic; perf-neutral:
// 768 blocks in one launch = 3 sequential 256-block rounds anyway).
__global__ __launch_bounds__(512, 2)
void qkv_gemm(const u16t* __restrict__ xb, const u16t* __restrict__ w,
              const float* __restrict__ bias, u16t* __restrict__ out, int rope,
              const float* __restrict__ fcos, const float* __restrict__ fsin) {
    __shared__ u16t lds[65536];     // 128 KiB: 2 dbuf x (A k0,k1 + B k0,k1)
    facc4 acc[8][4];
    int bm0, bn0; tile_swz(bm0, bn0);
    gemm256(xb, w, bm0, bn0, lds, acc);

    const int t     = threadIdx.x;
    const int lane  = t & 63;
    const int m16   = lane & 15;
    const int quad  = lane >> 4;
    const int wid   = t >> 6;
    const int wid_m = wid >> 2;
    const int wid_n = wid & 3;

#pragma unroll
    for (int i = 0; i < 8; ++i) {
#pragma unroll
        for (int j = 0; j < 4; ++j) {
            const int n = bn0 + wid_n * 64 + j * 16 + m16;
            const float bn_ = bias[n];
#pragma unroll
            for (int r = 0; r < 4; ++r) {
                const int m = bm0 + wid_m * 128 + i * 16 + quad * 4 + r;
                float v = acc[i][j][r] + bn_;
                // RoPE: pair partner (n^1) lives in lane^1 (same quad, same reg)
                const float part = __shfl_xor(v, 1, 64);
                if (rope) {
                    const int s = m & (S_LEN - 1);
                    const int p = (n & 127) >> 1;
                    const float cs = fcos[s * 64 + p];
                    const float sn = fsin[s * 64 + p];
                    v = (n & 1) ? (part * sn + v * cs) : (v * cs - part * sn);
                }
                out[(size_t)m * E_DIM + n] = f2bf(v);
            }
        }
    }
}

// ---------------- output projection GEMM (fp32 out + bias) ----------------
__global__ __launch_bounds__(512, 2)
void out_gemm(const u16t* __restrict__ sh, const u16t* __restrict__ wob,
              const float* __restrict__ bo, float* __restrict__ out) {
    __shared__ u16t lds[65536];
    facc4 acc[8][4];
    int bm0, bn0; tile_swz(bm0, bn0);
    gemm256(sh, wob, bm0, bn0, lds, acc);

    const int t     = threadIdx.x;
    const int lane  = t & 63;
    const int m16   = lane & 15;
    const int quad  = lane >> 4;
    const int wid   = t >> 6;
    const int wid_m = wid >> 2;
    const int wid_n = wid & 3;

#pragma unroll
    for (int i = 0; i < 8; ++i) {
#pragma unroll
        for (int j = 0; j < 4; ++j) {
            const int n = bn0 + wid_n * 64 + j * 16 + m16;
            const float bn_ = bo[n];
#pragma unroll
            for (int r = 0; r < 4; ++r) {
                const int m = bm0 + wid_m * 128 + i * 16 + quad * 4 + r;
                out[(size_t)m * E_DIM + n] = acc[i][j][r] + bn_;
            }
        }
    }
}

// ---------------- per-token head attention, MFMA version ----------------
// One WAVE per token. Change vs R4: PV MFMA operands SWAPPED --
// oacc = mfma(A=V-frag, B=P-frag) (A/B frag layouts are symmetric, same
// trick as QK^T). Resulting D layout: col = h = m16, row = d = quad*4+r,
// so each lane holds 4 CONSECUTIVE d values -> pack into one ushort4
// store per dblk. This deletes the whole output LDS staging path
// (32 ds_write + 4 ds_read per lane) and the P zero-pad still cancels
// the V-gather garbage for k>=16 (now on the A side).
__global__ __launch_bounds__(256)
void attn_kernel(const u16t* __restrict__ qb, const u16t* __restrict__ kb,
                 const u16t* __restrict__ vb, u16t* __restrict__ sh) {
    __shared__ u16t Vs[4][16 * 136];   // pad 136: 4-way worst on frag reads
    __shared__ u16t Pt[4][16 * 32];    // P in A-frag layout, cols 16..31 = 0

    const int t    = threadIdx.x;
    const int wid  = t >> 6;
    const int lane = t & 63;
    const int m16  = lane & 15;
    const int quad = lane >> 4;
    const int tk   = blockIdx.x * 4 + wid;
    const int b    = tk >> 11;
    const int s    = tk & (S_LEN - 1);
    const size_t row = (size_t)tk * E_DIM;

    // Q,K fragments straight from global (16B per lane per k-step)
    frag8 aq[4], ak[4];
    const u16t* qrow = qb + row + m16 * 128 + quad * 8;
    const u16t* krow = kb + row + m16 * 128 + quad * 8;
#pragma unroll
    for (int ks = 0; ks < 4; ++ks) {
        aq[ks] = *(const frag8*)(qrow + ks * 32);
        ak[ks] = *(const frag8*)(krow + ks * 32);
    }

    // V row -> LDS [16][136]
    u16t* vs = Vs[wid];
#pragma unroll
    for (int c = 0; c < 4; ++c) {
        const int e  = c * 512 + lane * 8;
        const int vr = e >> 7, vc = e & 127;
        *(uint4*)(vs + vr * 136 + vc) = *(const uint4*)(vb + row + e);
    }

    // scores
    facc4 sacc = facc4{0.f, 0.f, 0.f, 0.f};
#pragma unroll
    for (int ks = 0; ks < 4; ++ks)
        sacc = __builtin_amdgcn_mfma_f32_16x16x32_bf16(aq[ks], ak[ks], sacc, 0, 0, 0);

    // softmax over g (16 lanes of the same quad); lane holds rows h=quad*4+r at col g=m16
    float p[4], mx[4], sm[4];
#pragma unroll
    for (int r = 0; r < 4; ++r) { p[r] = sacc[r] * 0.08838834764831845f; mx[r] = p[r]; }
#pragma unroll
    for (int msk = 1; msk < 16; msk <<= 1)
#pragma unroll
        for (int r = 0; r < 4; ++r) mx[r] = fmaxf(mx[r], __shfl_xor(mx[r], msk, 64));
#pragma unroll
    for (int r = 0; r < 4; ++r) { p[r] = __expf(p[r] - mx[r]); sm[r] = p[r]; }
#pragma unroll
    for (int msk = 1; msk < 16; msk <<= 1)
#pragma unroll
        for (int r = 0; r < 4; ++r) sm[r] += __shfl_xor(sm[r], msk, 64);

    // P -> LDS in frag layout: Pt[h][g], h rows of 32 (cols 16..31 zero)
    u16t* pt = Pt[wid];
#pragma unroll
    for (int r = 0; r < 4; ++r)
        pt[(quad * 4 + r) * 32 + m16] = f2bf(p[r] / sm[r]);
    *(uint2*)(pt + m16 * 32 + 16 + quad * 4) = uint2{0u, 0u};   // zero pad

    // B-frag of P: lane holds P[m16][quad*8+j]  (same-wave LDS dep, no barrier)
    const frag8 aP = *(const frag8*)(pt + m16 * 32 + quad * 8);

    // PV (swapped): A-frag j = V[(quad*8+j)&15][dblk*16+m16]; B-frag = P.
    // D: lane holds out[h=m16][d = dblk*16 + quad*4 + r]
    facc4 oacc[8];
#pragma unroll
    for (int d = 0; d < 8; ++d) oacc[d] = facc4{0.f, 0.f, 0.f, 0.f};
#pragma unroll
    for (int dblk = 0; dblk < 8; ++dblk) {
        union { u16t u[8]; frag8 f; } bb;
#pragma unroll
        for (int j = 0; j < 8; ++j)
            bb.u[j] = vs[((quad * 8 + j) & 15) * 136 + dblk * 16 + m16];
        oacc[dblk] = __builtin_amdgcn_mfma_f32_16x16x32_bf16(bb.f, aP, oacc[dblk], 0, 0, 0);
    }

    // direct packed stores: per dblk one ushort4 (4 consecutive d per lane)
    const size_t base = ((size_t)b << 22) + (size_t)(s >> 4) * E_DIM
                      + (size_t)((s & 15) * 128) + ((size_t)m16 << 18);
#pragma unroll
    for (int dblk = 0; dblk < 8; ++dblk) {
        ushort4 o;
        o.x = f2bf(oacc[dblk][0]); o.y = f2bf(oacc[dblk][1]);
        o.z = f2bf(oacc[dblk][2]); o.w = f2bf(oacc[dblk][3]);
        *(ushort4*)(sh + base + dblk * 16 + quad * 4) = o;
    }
}

// ---------------- launch ----------------
extern "C" void kernel_launch(void* const* d_in, const int* in_sizes, int n_in,
                              void* d_out, int out_size, void* d_ws, size_t ws_size,
                              hipStream_t stream) {
    const float* x    = (const float*)d_in[0];
    const float* fcos = (const float*)d_in[1];
    const float* fsin = (const float*)d_in[2];
    const float* wq   = (const float*)d_in[3];
    const float* bq   = (const float*)d_in[4];
    const float* wk   = (const float*)d_in[5];
    const float* bk   = (const float*)d_in[6];
    const float* wv   = (const float*)d_in[7];
    const float* bv   = (const float*)d_in[8];
    const float* wo   = (const float*)d_in[9];
    const float* bo   = (const float*)d_in[10];
    float* out = (float*)d_out;

    char* ws = (char*)d_ws;
    u16t* xb  = (u16t*)(ws);                      // 32 MB, reused as shuffled buf
    u16t* qb  = (u16t*)(ws + 33554432ull);
    u16t* kb  = (u16t*)(ws + 67108864ull);
    u16t* vb  = (u16t*)(ws + 100663296ull);
    u16t* wqb = (u16t*)(ws + 134217728ull);
    u16t* wkb = (u16t*)(ws + 142606336ull);
    u16t* wvb = (u16t*)(ws + 150994944ull);
    u16t* wob = (u16t*)(ws + 159383552ull);       // total 160 MB

    cvt_kernel<<<16384, 256, 0, stream>>>(x, xb, 4194304);
    cvt_kernel<<<4096, 256, 0, stream>>>(wq, wqb, 1048576);
    cvt_kernel<<<4096, 256, 0, stream>>>(wk, wkb, 1048576);
    cvt_kernel<<<4096, 256, 0, stream>>>(wv, wvb, 1048576);
    cvt_kernel<<<4096, 256, 0, stream>>>(wo, wob, 1048576);

    qkv_gemm<<<dim3(8, 32), 512, 0, stream>>>(xb, wqb, bq, qb, 1, fcos, fsin);
    qkv_gemm<<<dim3(8, 32), 512, 0, stream>>>(xb, wkb, bk, kb, 1, fcos, fsin);
    qkv_gemm<<<dim3(8, 32), 512, 0, stream>>>(xb, wvb, bv, vb, 0, fcos, fsin);

    attn_kernel<<<2048, 256, 0, stream>>>(qb, kb, vb, xb);

    out_gemm<<<dim3(8, 32), 512, 0, stream>>>(xb, wob, bo, out);
}